// Round 5
// baseline (510.479 us; speedup 1.0000x reference)
//
#include <hip/hip_runtime.h>
#include <math.h>

#define N_NODES   100000
#define N_EDGES   1600000
#define NODE_F    128
#define EDGE_F    128
#define GLOB_F    64
#define N_GRAPHS  256
#define HIDDEN    128
#define IN_DIM    320   // 128 + 128 + 64

#define SCAN_T 1024
#define SCAN_C 98     // ceil(100000/1024)

typedef __bf16 bf16x8 __attribute__((ext_vector_type(8)));
typedef __bf16 bf16x4 __attribute__((ext_vector_type(4)));
typedef float  f32x4  __attribute__((ext_vector_type(4)));

__device__ __forceinline__ void cvt_store4(__bf16* p, float x, float y, float z, float w) {
    bf16x4 b = { (__bf16)x, (__bf16)y, (__bf16)z, (__bf16)w };
    *reinterpret_cast<bf16x4*>(p) = b;
}

// ---------------------------------------------------------------------------
// W (f32 [128,320]) -> bf16, once.
// ---------------------------------------------------------------------------
__global__ __launch_bounds__(256) void wbf_kernel(const float* __restrict__ W,
                                                  __bf16* __restrict__ wbf) {
    int i = blockIdx.x * 256 + threadIdx.x;   // 160 blocks x 256 = 40960 exact
    wbf[i] = (__bf16)W[i];
}

// ---------------------------------------------------------------------------
// CSR build: histogram(+rank) -> single-block scan -> fill (atomic-free)
// ---------------------------------------------------------------------------
__global__ __launch_bounds__(256) void hist_kernel(const int* __restrict__ dst,
                                                   int* __restrict__ counts,
                                                   int* __restrict__ rank) {
    int i = blockIdx.x * 256 + threadIdx.x;   // 6250 x 256 = 1.6M exact
    if (i < N_EDGES) rank[i] = atomicAdd(&counts[dst[i]], 1);
}

__global__ __launch_bounds__(SCAN_T) void scan_kernel(const int* __restrict__ counts,
                                                      int* __restrict__ offs) {
    __shared__ int ts[SCAN_T];
    const int tid  = threadIdx.x;
    const int base = tid * SCAN_C;
    int s = 0;
    for (int j = 0; j < SCAN_C; ++j) {
        int idx = base + j;
        if (idx < N_NODES) s += counts[idx];
    }
    ts[tid] = s;
    __syncthreads();
    for (int off = 1; off < SCAN_T; off <<= 1) {
        int v = (tid >= off) ? ts[tid - off] : 0;
        __syncthreads();
        ts[tid] += v;
        __syncthreads();
    }
    int run = ts[tid] - s;   // exclusive prefix of this thread's chunk
    for (int j = 0; j < SCAN_C; ++j) {
        int idx = base + j;
        if (idx < N_NODES) { int c = counts[idx]; offs[idx] = run; run += c; }
    }
    if (tid == 0) offs[N_NODES] = N_EDGES;
}

__global__ __launch_bounds__(256) void fill_kernel(const int* __restrict__ dst,
                                                   const int* __restrict__ rank,
                                                   const int* __restrict__ offs,
                                                   int* __restrict__ eid) {
    int i = blockIdx.x * 256 + threadIdx.x;
    if (i < N_EDGES) {
        int d = dst[i];
        eid[offs[d] + rank[i]] = i;
    }
}

// ---------------------------------------------------------------------------
// Fused: CSR gather-mean + concat (into LDS as bf16) + MFMA GEMM + softplus.
// Block = 256 threads (4 waves), 32 rows x 128 cols of output.
// Gather: wave = 4 x 16-lane groups; group processes its two rows one at a
// time with a 16-edge unrolled, guarded (junk-free) inner loop; both rows'
// offs + first eid batches are issued at the TOP of the kernel so the second
// row's index chain is already in flight during staging and row 0's loop.
// GEMM: A from LDS, B (W) read directly from global bf16 copy; barrier-free.
// ---------------------------------------------------------------------------
#define ROWS 32
#define XSTR (IN_DIM + 8)     // 328 bf16 -> 656 B row stride (16B-aligned)

__global__ __launch_bounds__(256) void fused_kernel(
    const float* __restrict__ node_feats,   // [N_NODES,128]
    const float* __restrict__ edge_feats,   // [N_EDGES,128]
    const float* __restrict__ glob,         // [256,64]
    const int*   __restrict__ batch,        // [N_NODES]
    const __bf16* __restrict__ wbf,         // [128,320] bf16
    const int*   __restrict__ offs,         // [N_NODES+1]
    const int*   __restrict__ eid,          // [N_EDGES]
    float* __restrict__ out)                // [N_NODES,128]
{
    __shared__ __bf16 xs[ROWS * XSTR];      // 20992 B (only LDS use)

    const int tid  = threadIdx.x;
    const int row0 = blockIdx.x * ROWS;
    const int wv   = tid >> 6;
    const int lane = tid & 63;
    const int gl   = lane & 15;             // lane within 16-group
    const int grp  = lane >> 4;             // group 0..3

    // ---- this group's two rows; issue offs + first eid batches FIRST
    const int r0 = wv * 8 + grp;
    const int r1 = r0 + 4;
    const int beg0 = offs[row0 + r0], end0 = offs[row0 + r0 + 1];
    const int beg1 = offs[row0 + r1], end1 = offs[row0 + r1 + 1];
    const int E0 = end0 - beg0, E1 = end1 - beg1;
    const int lim0 = max(end0 - 1, 0);
    const int lim1 = max(end1 - 1, 0);
    int ev0 = eid[min(beg0 + gl, lim0)];
    int ev1 = eid[min(beg1 + gl, lim1)];    // row 1's chain in flight early

    // ---- stage node features -> xs[:, 0:128)
    #pragma unroll
    for (int it = 0; it < 4; ++it) {
        int i = tid + it * 256;             // 0..1023
        int r = i >> 5, k4 = i & 31;
        float4 v = *reinterpret_cast<const float4*>(
            node_feats + (size_t)(row0 + r) * NODE_F + k4 * 4);
        cvt_store4(&xs[r * XSTR + k4 * 4], v.x, v.y, v.z, v.w);
    }
    // ---- stage globals -> xs[:, 256:320)
    #pragma unroll
    for (int it = 0; it < 2; ++it) {
        int i = tid + it * 256;             // 0..511
        int r = i >> 4, k4 = i & 15;
        int b = batch[row0 + r];
        float4 v = *reinterpret_cast<const float4*>(
            glob + (size_t)b * GLOB_F + k4 * 4);
        cvt_store4(&xs[r * XSTR + NODE_F + EDGE_F + k4 * 4], v.x, v.y, v.z, v.w);
    }

    // ---- gather-mean row 0
    {
        float a0=0.f,a1=0.f,a2=0.f,a3=0.f,a4=0.f,a5=0.f,a6=0.f,a7=0.f;
        for (int c0 = 0; c0 < E0; c0 += 16) {
            #pragma unroll
            for (int i = 0; i < 16; ++i) {
                int e = __shfl(ev0, (lane & 48) + i);
                if (c0 + i < E0) {
                    const f32x4* p = reinterpret_cast<const f32x4*>(
                        edge_feats + (size_t)e * EDGE_F + gl * 8);
                    f32x4 u0 = p[0];
                    f32x4 u1 = p[1];
                    a0 += u0.x; a1 += u0.y; a2 += u0.z; a3 += u0.w;
                    a4 += u1.x; a5 += u1.y; a6 += u1.z; a7 += u1.w;
                }
            }
            ev0 = eid[min(beg0 + c0 + 16 + gl, lim0)];
        }
        float ic = 1.0f / fmaxf((float)E0, 1.0f);
        bf16x8 b;
        b[0]=(__bf16)(a0*ic); b[1]=(__bf16)(a1*ic);
        b[2]=(__bf16)(a2*ic); b[3]=(__bf16)(a3*ic);
        b[4]=(__bf16)(a4*ic); b[5]=(__bf16)(a5*ic);
        b[6]=(__bf16)(a6*ic); b[7]=(__bf16)(a7*ic);
        *reinterpret_cast<bf16x8*>(&xs[r0 * XSTR + NODE_F + gl * 8]) = b;
    }
    // ---- gather-mean row 1 (first batch already prefetched)
    {
        float a0=0.f,a1=0.f,a2=0.f,a3=0.f,a4=0.f,a5=0.f,a6=0.f,a7=0.f;
        for (int c0 = 0; c0 < E1; c0 += 16) {
            #pragma unroll
            for (int i = 0; i < 16; ++i) {
                int e = __shfl(ev1, (lane & 48) + i);
                if (c0 + i < E1) {
                    const f32x4* p = reinterpret_cast<const f32x4*>(
                        edge_feats + (size_t)e * EDGE_F + gl * 8);
                    f32x4 u0 = p[0];
                    f32x4 u1 = p[1];
                    a0 += u0.x; a1 += u0.y; a2 += u0.z; a3 += u0.w;
                    a4 += u1.x; a5 += u1.y; a6 += u1.z; a7 += u1.w;
                }
            }
            ev1 = eid[min(beg1 + c0 + 16 + gl, lim1)];
        }
        float ic = 1.0f / fmaxf((float)E1, 1.0f);
        bf16x8 b;
        b[0]=(__bf16)(a0*ic); b[1]=(__bf16)(a1*ic);
        b[2]=(__bf16)(a2*ic); b[3]=(__bf16)(a3*ic);
        b[4]=(__bf16)(a4*ic); b[5]=(__bf16)(a5*ic);
        b[6]=(__bf16)(a6*ic); b[7]=(__bf16)(a7*ic);
        *reinterpret_cast<bf16x8*>(&xs[r1 * XSTR + NODE_F + gl * 8]) = b;
    }

    __syncthreads();   // xs complete; k-loop below is barrier-free

    f32x4 acc00 = {0.f, 0.f, 0.f, 0.f};
    f32x4 acc10 = {0.f, 0.f, 0.f, 0.f};
    f32x4 acc01 = {0.f, 0.f, 0.f, 0.f};
    f32x4 acc11 = {0.f, 0.f, 0.f, 0.f};

    const int lr = lane & 15;    // row/col within MFMA tile
    const int kb = lane >> 4;    // k-block of 8

    const __bf16* wrow0 = wbf + (size_t)(wv * 32 + lr) * IN_DIM + kb * 8;
    const __bf16* wrow1 = wrow0 + 16 * IN_DIM;

    #pragma unroll 2
    for (int kt = 0; kt < IN_DIM / 32; ++kt) {     // 10 k-steps
        bf16x8 a0 = *reinterpret_cast<const bf16x8*>(&xs[lr * XSTR + kt * 32 + kb * 8]);
        bf16x8 a1 = *reinterpret_cast<const bf16x8*>(&xs[(16 + lr) * XSTR + kt * 32 + kb * 8]);
        bf16x8 b0 = *reinterpret_cast<const bf16x8*>(wrow0 + kt * 32);
        bf16x8 b1 = *reinterpret_cast<const bf16x8*>(wrow1 + kt * 32);

        acc00 = __builtin_amdgcn_mfma_f32_16x16x32_bf16(a0, b0, acc00, 0, 0, 0);
        acc10 = __builtin_amdgcn_mfma_f32_16x16x32_bf16(a1, b0, acc10, 0, 0, 0);
        acc01 = __builtin_amdgcn_mfma_f32_16x16x32_bf16(a0, b1, acc01, 0, 0, 0);
        acc11 = __builtin_amdgcn_mfma_f32_16x16x32_bf16(a1, b1, acc11, 0, 0, 0);
    }

    // ---- epilogue: shifted softplus, C/D layout col=lane&15, row=(lane>>4)*4+q
    const float LN2 = 0.69314718055994530942f;
#define EMIT(ACC, RT, CT)                                                      \
    do {                                                                       \
        int col = (wv * 2 + (CT)) * 16 + lr;                                   \
        _Pragma("unroll")                                                      \
        for (int q = 0; q < 4; ++q) {                                          \
            int row = row0 + (RT) * 16 + kb * 4 + q;                           \
            float h = ACC[q];                                                  \
            float sp = fmaxf(h, 0.f) + log1pf(__expf(-fabsf(h)));              \
            out[(size_t)row * HIDDEN + col] = sp - LN2;                        \
        }                                                                      \
    } while (0)
    EMIT(acc00, 0, 0);
    EMIT(acc10, 1, 0);
    EMIT(acc01, 0, 1);
    EMIT(acc11, 1, 1);
#undef EMIT
}

// ---------------------------------------------------------------------------
extern "C" void kernel_launch(void* const* d_in, const int* in_sizes, int n_in,
                              void* d_out, int out_size, void* d_ws, size_t ws_size,
                              hipStream_t stream) {
    const float* node_feats = (const float*)d_in[0];   // [100000,128]
    const float* edge_feats = (const float*)d_in[1];   // [1600000,128]
    const float* glob       = (const float*)d_in[2];   // [256,64]
    const float* W          = (const float*)d_in[3];   // [128,320]
    const int*   edge_index = (const int*)d_in[4];     // [2,1600000]
    const int*   batch      = (const int*)d_in[5];     // [100000]
    float* out = (float*)d_out;                        // [100000,128]

    const int* dst = edge_index + N_EDGES;             // row 1 = destinations

    // workspace layout
    __bf16* wbf = (__bf16*)d_ws;                       // 40960 bf16 = 81920 B
    int* ws_i   = (int*)((char*)d_ws + 81920);
    int* counts  = ws_i;                               // 100000
    int* offs    = ws_i + 100000;                      // 100001
    int* eid     = ws_i + 200002;                      // 1600000
    int* rank    = ws_i + 1800002;                     // 1600000  (ends ~13.7 MB)

    hipMemsetAsync(counts, 0, (size_t)N_NODES * sizeof(int), stream);

    wbf_kernel<<<160, 256, 0, stream>>>(W, wbf);
    hist_kernel<<<N_EDGES / 256, 256, 0, stream>>>(dst, counts, rank);
    scan_kernel<<<1, SCAN_T, 0, stream>>>(counts, offs);
    fill_kernel<<<N_EDGES / 256, 256, 0, stream>>>(dst, rank, offs, eid);

    fused_kernel<<<N_NODES / ROWS, 256, 0, stream>>>(
        node_feats, edge_feats, glob, batch, wbf, offs, eid, out);
}

// Round 6
// 350.411 us; speedup vs baseline: 1.4568x; 1.4568x over previous
//
#include <hip/hip_runtime.h>
#include <math.h>

#define N_NODES   100000
#define N_EDGES   1600000
#define NODE_F    128
#define EDGE_F    128
#define GLOB_F    64
#define N_GRAPHS  256
#define HIDDEN    128
#define IN_DIM    320   // 128 + 128 + 64

#define SCAN_CHUNK 2048
#define NSCAN ((N_NODES + SCAN_CHUNK - 1) / SCAN_CHUNK)   // 49

typedef __bf16 bf16x8 __attribute__((ext_vector_type(8)));
typedef __bf16 bf16x4 __attribute__((ext_vector_type(4)));
typedef float  f32x4  __attribute__((ext_vector_type(4)));

__device__ __forceinline__ void cvt_store4(__bf16* p, float x, float y, float z, float w) {
    bf16x4 b = { (__bf16)x, (__bf16)y, (__bf16)z, (__bf16)w };
    *reinterpret_cast<bf16x4*>(p) = b;
}

// ---------------------------------------------------------------------------
// W (f32 [128,320]) -> bf16, once.
// ---------------------------------------------------------------------------
__global__ __launch_bounds__(256) void wbf_kernel(const float* __restrict__ W,
                                                  __bf16* __restrict__ wbf) {
    int i = blockIdx.x * 256 + threadIdx.x;   // 160 blocks x 256 = 40960 exact
    wbf[i] = (__bf16)W[i];
}

// ---------------------------------------------------------------------------
// CSR build: histogram(+rank) -> 3-kernel scan (round-3 proven) -> rank fill
// ---------------------------------------------------------------------------
__global__ __launch_bounds__(256) void hist_kernel(const int* __restrict__ dst,
                                                   int* __restrict__ counts,
                                                   int* __restrict__ rank) {
    int i = blockIdx.x * 256 + threadIdx.x;   // 6250 x 256 = 1.6M exact
    if (i < N_EDGES) rank[i] = atomicAdd(&counts[dst[i]], 1);
}

__global__ __launch_bounds__(256) void scan1_kernel(const int* __restrict__ counts,
                                                    int* __restrict__ partial) {
    __shared__ int red[256];
    int tid = threadIdx.x;
    int base = blockIdx.x * SCAN_CHUNK + tid * 8;
    int s = 0;
    #pragma unroll
    for (int j = 0; j < 8; ++j) {
        int idx = base + j;
        if (idx < N_NODES) s += counts[idx];
    }
    red[tid] = s;
    __syncthreads();
    for (int off = 128; off > 0; off >>= 1) {
        if (tid < off) red[tid] += red[tid + off];
        __syncthreads();
    }
    if (tid == 0) partial[blockIdx.x] = red[0];
}

__global__ __launch_bounds__(64) void scan2_kernel(const int* __restrict__ partial,
                                                   int* __restrict__ pscan) {
    if (threadIdx.x == 0) {
        int run = 0;
        for (int b = 0; b < NSCAN; ++b) { pscan[b] = run; run += partial[b]; }
    }
}

__global__ __launch_bounds__(256) void scan3_kernel(const int* __restrict__ counts,
                                                    const int* __restrict__ pscan,
                                                    int* __restrict__ offs) {
    __shared__ int ts[256];
    int tid = threadIdx.x;
    int base = blockIdx.x * SCAN_CHUNK + tid * 8;
    int c[8];
    int tot = 0;
    #pragma unroll
    for (int j = 0; j < 8; ++j) {
        int idx = base + j;
        c[j] = (idx < N_NODES) ? counts[idx] : 0;
        tot += c[j];
    }
    ts[tid] = tot;
    __syncthreads();
    for (int off = 1; off < 256; off <<= 1) {
        int v = 0;
        if (tid >= off) v = ts[tid - off];
        __syncthreads();
        if (tid >= off) ts[tid] += v;
        __syncthreads();
    }
    int run = pscan[blockIdx.x] + ts[tid] - tot;   // exclusive prefix
    #pragma unroll
    for (int j = 0; j < 8; ++j) {
        int idx = base + j;
        if (idx < N_NODES) { offs[idx] = run; run += c[j]; }
    }
    if (blockIdx.x == 0 && tid == 0) offs[N_NODES] = N_EDGES;
}

__global__ __launch_bounds__(256) void fill_kernel(const int* __restrict__ dst,
                                                   const int* __restrict__ rank,
                                                   const int* __restrict__ offs,
                                                   int* __restrict__ eid) {
    int i = blockIdx.x * 256 + threadIdx.x;
    if (i < N_EDGES) {
        int d = dst[i];
        eid[offs[d] + rank[i]] = i;
    }
}

// ---------------------------------------------------------------------------
// Gather-mean kernel (dedicated, high-occupancy): one node per 16-lane group,
// 16 groups per 256-thread block, zero LDS, small VGPR footprint.
// Writes mean as bf16 [N_NODES,128] (coalesced 256B per group).
// ---------------------------------------------------------------------------
__global__ __launch_bounds__(256, 6) void gather_kernel(
    const float* __restrict__ edge_feats,   // [N_EDGES,128]
    const int*   __restrict__ offs,         // [N_NODES+1]
    const int*   __restrict__ eid,          // [N_EDGES]
    __bf16* __restrict__ mean_bf)           // [N_NODES,128]
{
    const int tid  = threadIdx.x;
    const int lane = tid & 63;
    const int gl   = lane & 15;             // lane within 16-group
    const int n    = blockIdx.x * 16 + (tid >> 4);   // node id, 6250 blocks exact

    const int beg = offs[n], end = offs[n + 1];
    const int E   = end - beg;
    const int lim = max(end - 1, 0);
    int ev = eid[min(beg + gl, lim)];

    float a0=0.f,a1=0.f,a2=0.f,a3=0.f,a4=0.f,a5=0.f,a6=0.f,a7=0.f;
    for (int c0 = 0; c0 < E; c0 += 16) {
        #pragma unroll
        for (int i = 0; i < 16; ++i) {
            int e = __shfl(ev, (lane & 48) + i);
            if (c0 + i < E) {
                const f32x4* p = reinterpret_cast<const f32x4*>(
                    edge_feats + (size_t)e * EDGE_F + gl * 8);
                f32x4 u0 = p[0];
                f32x4 u1 = p[1];
                a0 += u0.x; a1 += u0.y; a2 += u0.z; a3 += u0.w;
                a4 += u1.x; a5 += u1.y; a6 += u1.z; a7 += u1.w;
            }
        }
        ev = eid[min(beg + c0 + 16 + gl, lim)];
    }
    float ic = 1.0f / fmaxf((float)E, 1.0f);
    bf16x8 b;
    b[0]=(__bf16)(a0*ic); b[1]=(__bf16)(a1*ic);
    b[2]=(__bf16)(a2*ic); b[3]=(__bf16)(a3*ic);
    b[4]=(__bf16)(a4*ic); b[5]=(__bf16)(a5*ic);
    b[6]=(__bf16)(a6*ic); b[7]=(__bf16)(a7*ic);
    *reinterpret_cast<bf16x8*>(mean_bf + (size_t)n * EDGE_F + gl * 8) = b;
}

// ---------------------------------------------------------------------------
// GEMM kernel: concat (node f32->bf16, mean bf16 copy, glob f32->bf16) into
// LDS, barrier-free MFMA k-loop (B direct from L2-resident bf16 W), shifted
// softplus epilogue. Block = 256 threads (4 waves), 32 rows x 128 cols.
// ---------------------------------------------------------------------------
#define ROWS 32
#define XSTR (IN_DIM + 8)     // 328 bf16 -> 656 B row stride (16B-aligned)

__global__ __launch_bounds__(256) void gemm_kernel(
    const float* __restrict__ node_feats,   // [N_NODES,128]
    const __bf16* __restrict__ mean_bf,     // [N_NODES,128]
    const float* __restrict__ glob,         // [256,64]
    const int*   __restrict__ batch,        // [N_NODES]
    const __bf16* __restrict__ wbf,         // [128,320] bf16
    float* __restrict__ out)                // [N_NODES,128]
{
    __shared__ __bf16 xs[ROWS * XSTR];      // 20992 B

    const int tid  = threadIdx.x;
    const int row0 = blockIdx.x * ROWS;
    const int wv   = tid >> 6;
    const int lane = tid & 63;

    // ---- stage node features -> xs[:, 0:128)
    #pragma unroll
    for (int it = 0; it < 4; ++it) {
        int i = tid + it * 256;             // 0..1023
        int r = i >> 5, k4 = i & 31;
        float4 v = *reinterpret_cast<const float4*>(
            node_feats + (size_t)(row0 + r) * NODE_F + k4 * 4);
        cvt_store4(&xs[r * XSTR + k4 * 4], v.x, v.y, v.z, v.w);
    }
    // ---- stage mean (already bf16) -> xs[:, 128:256)
    #pragma unroll
    for (int it = 0; it < 2; ++it) {
        int i = tid + it * 256;             // 0..511
        int r = i >> 4, c = i & 15;
        bf16x8 v = *reinterpret_cast<const bf16x8*>(
            mean_bf + (size_t)(row0 + r) * EDGE_F + c * 8);
        *reinterpret_cast<bf16x8*>(&xs[r * XSTR + NODE_F + c * 8]) = v;
    }
    // ---- stage globals -> xs[:, 256:320)
    #pragma unroll
    for (int it = 0; it < 2; ++it) {
        int i = tid + it * 256;             // 0..511
        int r = i >> 4, k4 = i & 15;
        int b = batch[row0 + r];
        float4 v = *reinterpret_cast<const float4*>(
            glob + (size_t)b * GLOB_F + k4 * 4);
        cvt_store4(&xs[r * XSTR + NODE_F + EDGE_F + k4 * 4], v.x, v.y, v.z, v.w);
    }

    __syncthreads();   // xs complete; k-loop below is barrier-free

    f32x4 acc00 = {0.f, 0.f, 0.f, 0.f};
    f32x4 acc10 = {0.f, 0.f, 0.f, 0.f};
    f32x4 acc01 = {0.f, 0.f, 0.f, 0.f};
    f32x4 acc11 = {0.f, 0.f, 0.f, 0.f};

    const int lr = lane & 15;    // row/col within MFMA tile
    const int kb = lane >> 4;    // k-block of 8

    const __bf16* wrow0 = wbf + (size_t)(wv * 32 + lr) * IN_DIM + kb * 8;
    const __bf16* wrow1 = wrow0 + 16 * IN_DIM;

    #pragma unroll 2
    for (int kt = 0; kt < IN_DIM / 32; ++kt) {     // 10 k-steps
        bf16x8 a0 = *reinterpret_cast<const bf16x8*>(&xs[lr * XSTR + kt * 32 + kb * 8]);
        bf16x8 a1 = *reinterpret_cast<const bf16x8*>(&xs[(16 + lr) * XSTR + kt * 32 + kb * 8]);
        bf16x8 b0 = *reinterpret_cast<const bf16x8*>(wrow0 + kt * 32);
        bf16x8 b1 = *reinterpret_cast<const bf16x8*>(wrow1 + kt * 32);

        acc00 = __builtin_amdgcn_mfma_f32_16x16x32_bf16(a0, b0, acc00, 0, 0, 0);
        acc10 = __builtin_amdgcn_mfma_f32_16x16x32_bf16(a1, b0, acc10, 0, 0, 0);
        acc01 = __builtin_amdgcn_mfma_f32_16x16x32_bf16(a0, b1, acc01, 0, 0, 0);
        acc11 = __builtin_amdgcn_mfma_f32_16x16x32_bf16(a1, b1, acc11, 0, 0, 0);
    }

    // ---- epilogue: shifted softplus, C/D layout col=lane&15, row=(lane>>4)*4+q
    const float LN2 = 0.69314718055994530942f;
#define EMIT(ACC, RT, CT)                                                      \
    do {                                                                       \
        int col = (wv * 2 + (CT)) * 16 + lr;                                   \
        _Pragma("unroll")                                                      \
        for (int q = 0; q < 4; ++q) {                                          \
            int row = row0 + (RT) * 16 + kb * 4 + q;                           \
            float h = ACC[q];                                                  \
            float sp = fmaxf(h, 0.f) + log1pf(__expf(-fabsf(h)));              \
            out[(size_t)row * HIDDEN + col] = sp - LN2;                        \
        }                                                                      \
    } while (0)
    EMIT(acc00, 0, 0);
    EMIT(acc10, 1, 0);
    EMIT(acc01, 0, 1);
    EMIT(acc11, 1, 1);
#undef EMIT
}

// ---------------------------------------------------------------------------
extern "C" void kernel_launch(void* const* d_in, const int* in_sizes, int n_in,
                              void* d_out, int out_size, void* d_ws, size_t ws_size,
                              hipStream_t stream) {
    const float* node_feats = (const float*)d_in[0];   // [100000,128]
    const float* edge_feats = (const float*)d_in[1];   // [1600000,128]
    const float* glob       = (const float*)d_in[2];   // [256,64]
    const float* W          = (const float*)d_in[3];   // [128,320]
    const int*   edge_index = (const int*)d_in[4];     // [2,1600000]
    const int*   batch      = (const int*)d_in[5];     // [100000]
    float* out = (float*)d_out;                        // [100000,128]

    const int* dst = edge_index + N_EDGES;             // row 1 = destinations

    // workspace layout (16B-aligned chunks)
    __bf16* wbf     = (__bf16*)d_ws;                              // 81,920 B
    __bf16* mean_bf = (__bf16*)((char*)d_ws + 81920);             // 25,600,000 B
    int* ws_i       = (int*)((char*)d_ws + 81920 + 25600000);
    int* counts  = ws_i;                               // 100000
    int* partial = ws_i + 100000;                      // 64
    int* pscan   = ws_i + 100064;                      // 64
    int* offs    = ws_i + 100128;                      // 100001
    int* eid     = ws_i + 200132;                      // 1600000
    int* rank    = ws_i + 1800132;                     // 1600000  (ends ~39 MB)

    hipMemsetAsync(counts, 0, (size_t)N_NODES * sizeof(int), stream);

    wbf_kernel<<<160, 256, 0, stream>>>(W, wbf);
    hist_kernel<<<N_EDGES / 256, 256, 0, stream>>>(dst, counts, rank);
    scan1_kernel<<<NSCAN, 256, 0, stream>>>(counts, partial);
    scan2_kernel<<<1, 64, 0, stream>>>(partial, pscan);
    scan3_kernel<<<NSCAN, 256, 0, stream>>>(counts, pscan, offs);
    fill_kernel<<<N_EDGES / 256, 256, 0, stream>>>(dst, rank, offs, eid);

    gather_kernel<<<N_NODES / 16, 256, 0, stream>>>(edge_feats, offs, eid, mean_bf);

    gemm_kernel<<<N_NODES / ROWS, 256, 0, stream>>>(
        node_feats, mean_bf, glob, batch, wbf, out);
}